// Round 2
// baseline (949.807 us; speedup 1.0000x reference)
//
#include <hip/hip_runtime.h>
#include <math.h>

#define NE 256
#define EDIM 1024
#define HW 1024
#define NPIX 16384
#define OUT_ELEMS 16777216

typedef short short8 __attribute__((ext_vector_type(8)));
typedef float f32x4 __attribute__((ext_vector_type(4)));

// ---------------- fast-path workspace layout (bytes) ----------------
#define WF_CE2    0          // float[256]
#define WF_HIST   1024       // int[256]
#define WF_LOSS   2048       // float
#define WF_ZSQ    2052       // float
#define WF_NFLAG  2056       // int
#define WF_FLAG   4096       // int[4096]
#define WF_IDX    20480      // int[16384]
#define WF_T      86016      // float[1024*256]
#define WF_EH     1134592    // ushort[256*1024]
#define WF_EL     1658880    // ushort[256*1024]
#define WF_NEED   2183168
#define WF_MEMSET 1134592    // control + flagged + idx + T
#define MAXF 4096
#define DELTA 0.25f

// ---------------- fallback (round-1) workspace layout ----------------
#define WO_CE2  0
#define WO_HIST 1024
#define WO_LOSS 2048
#define WO_IDX  4096
#define WO_T    69632
#define WO_TOTAL 1118208

#define APAD 40   // LDS row stride in bf16 elems: 80 B = 16B-aligned, ~2-way banks

__device__ __forceinline__ unsigned short f2bf(float f) {
    unsigned u = __float_as_uint(f);
    unsigned r = u + 0x7FFFu + ((u >> 16) & 1u);   // RNE
    return (unsigned short)(r >> 16);
}
__device__ __forceinline__ float bf2f(unsigned short h) {
    return __uint_as_float(((unsigned)h) << 16);
}

// ---------------- ce2[j] = 0.5*||emb_j||^2 (exact fp32) ----------------
__global__ __launch_bounds__(64) void k_norms(const float* __restrict__ emb,
                                              float* __restrict__ ce2) {
    int j = blockIdx.x;
    int lane = threadIdx.x;
    const float* row = emb + (size_t)j * EDIM;
    float s = 0.f;
    #pragma unroll
    for (int i = 0; i < EDIM / 64; i++) {
        float v = row[lane + 64 * i];
        s += v * v;
    }
    #pragma unroll
    for (int m = 32; m; m >>= 1) s += __shfl_down(s, m, 64);
    if (lane == 0) ce2[j] = 0.5f * s;
}

// ---------------- T[o][j] = sum_c w[o][c]*emb[j][c] (split-K, atomics) ----
__global__ __launch_bounds__(256) void k_wT(const float* __restrict__ w,
                                            const float* __restrict__ emb,
                                            float* __restrict__ T) {
    __shared__ float wt[64 * 17];
    __shared__ float et[64 * 17];
    int t = threadIdx.x;
    int j0 = blockIdx.x * 64;
    int o0 = blockIdx.y * 64;
    int kb = blockIdx.z * 256;
    int to = t & 15, tj = t >> 4;
    float acc[4][4] = {};
    int lr = t >> 2, lk = (t & 3) * 4;
    for (int kk = kb; kk < kb + 256; kk += 16) {
        float4 wv = *(const float4*)(w + (size_t)(o0 + lr) * EDIM + kk + lk);
        float4 ev = *(const float4*)(emb + (size_t)(j0 + lr) * EDIM + kk + lk);
        __syncthreads();
        wt[lr * 17 + lk + 0] = wv.x; wt[lr * 17 + lk + 1] = wv.y;
        wt[lr * 17 + lk + 2] = wv.z; wt[lr * 17 + lk + 3] = wv.w;
        et[lr * 17 + lk + 0] = ev.x; et[lr * 17 + lk + 1] = ev.y;
        et[lr * 17 + lk + 2] = ev.z; et[lr * 17 + lk + 3] = ev.w;
        __syncthreads();
        #pragma unroll
        for (int k = 0; k < 16; k++) {
            float a[4], b[4];
            #pragma unroll
            for (int i = 0; i < 4; i++) a[i] = wt[(to * 4 + i) * 17 + k];
            #pragma unroll
            for (int i = 0; i < 4; i++) b[i] = et[(tj * 4 + i) * 17 + k];
            #pragma unroll
            for (int i = 0; i < 4; i++)
                #pragma unroll
                for (int jx = 0; jx < 4; jx++) acc[i][jx] += a[i] * b[jx];
        }
    }
    #pragma unroll
    for (int i = 0; i < 4; i++)
        #pragma unroll
        for (int jx = 0; jx < 4; jx++)
            atomicAdd(&T[(size_t)(o0 + to * 4 + i) * NE + j0 + tj * 4 + jx],
                      acc[i][jx]);
}

// ---------------- prep: emb fp32 -> eh/el bf16 [code][k] -------------------
__global__ __launch_bounds__(256) void k_prep_e(const float* __restrict__ emb,
                                                unsigned short* __restrict__ eh,
                                                unsigned short* __restrict__ el) {
    int i = (blockIdx.x * 256 + threadIdx.x) * 4;
    float4 v = *(const float4*)(emb + i);
    unsigned short h0 = f2bf(v.x), h1 = f2bf(v.y), h2 = f2bf(v.z), h3 = f2bf(v.w);
    unsigned short l0 = f2bf(v.x - bf2f(h0)), l1 = f2bf(v.y - bf2f(h1));
    unsigned short l2 = f2bf(v.z - bf2f(h2)), l3 = f2bf(v.w - bf2f(h3));
    uint2 hp, lp;
    hp.x = (unsigned)h0 | ((unsigned)h1 << 16); hp.y = (unsigned)h2 | ((unsigned)h3 << 16);
    lp.x = (unsigned)l0 | ((unsigned)l1 << 16); lp.y = (unsigned)l2 | ((unsigned)l3 << 16);
    *(uint2*)(eh + i) = hp;
    *(uint2*)(el + i) = lp;
}

// ---------------- prep: z [b][c][p] -> zh/zl bf16 [px][k] + sum(z^2) -------
__global__ __launch_bounds__(256) void k_prep_z(const float* __restrict__ z,
                                                unsigned short* __restrict__ zh,
                                                unsigned short* __restrict__ zl,
                                                float* __restrict__ zsq_acc) {
    __shared__ float tile[64 * 69];
    __shared__ float sw[4];
    int t = threadIdx.x;
    int blk = blockIdx.x;                  // 4096 = 16b * 16 ctile * 16 ptile
    int b = blk >> 8;
    int ct0 = ((blk >> 4) & 15) * 64;
    int pt0 = (blk & 15) * 64;
    float s = 0.f;
    #pragma unroll
    for (int r = 0; r < 4; r++) {
        int c = r * 16 + (t >> 4);
        int px4 = (t & 15) * 4;
        float4 v = *(const float4*)(z + (((size_t)(b * 1024 + ct0 + c)) << 10) + pt0 + px4);
        *(float4*)(tile + c * 69 + px4) = v;
        s += v.x * v.x + v.y * v.y + v.z * v.z + v.w * v.w;
    }
    __syncthreads();
    int px = t >> 2, cg = t & 3;
    unsigned int hu[8], lu[8];
    #pragma unroll
    for (int i = 0; i < 8; i++) {
        float f0 = tile[(cg * 16 + 2 * i) * 69 + px];
        float f1 = tile[(cg * 16 + 2 * i + 1) * 69 + px];
        unsigned short h0 = f2bf(f0), h1 = f2bf(f1);
        unsigned short l0 = f2bf(f0 - bf2f(h0)), l1 = f2bf(f1 - bf2f(h1));
        hu[i] = (unsigned)h0 | ((unsigned)h1 << 16);
        lu[i] = (unsigned)l0 | ((unsigned)l1 << 16);
    }
    size_t base = (((size_t)(b * 1024 + pt0 + px)) << 10) + ct0 + cg * 16;
    *(uint4*)(zh + base)     = make_uint4(hu[0], hu[1], hu[2], hu[3]);
    *(uint4*)(zh + base + 8) = make_uint4(hu[4], hu[5], hu[6], hu[7]);
    *(uint4*)(zl + base)     = make_uint4(lu[0], lu[1], lu[2], lu[3]);
    *(uint4*)(zl + base + 8) = make_uint4(lu[4], lu[5], lu[6], lu[7]);
    #pragma unroll
    for (int m = 32; m; m >>= 1) s += __shfl_down(s, m, 64);
    if ((t & 63) == 0) sw[t >> 6] = s;
    __syncthreads();
    if (t == 0) atomicAdd(zsq_acc, sw[0] + sw[1] + sw[2] + sw[3]);
}

// ---------------- MFMA distance GEMM + argmin + tie-flagging ---------------
// grid 512 (32 px each), 256 thr (4 waves). Wave w: codes [w*64, w*64+64).
// bf16x3: S = zh*eh + zh*el + zl*eh. score s = 0.5||e||^2 - S; flag gap<DELTA.
__global__ __launch_bounds__(256) void k_dist(
        const unsigned short* __restrict__ zh, const unsigned short* __restrict__ zl,
        const unsigned short* __restrict__ eh, const unsigned short* __restrict__ el,
        const float* __restrict__ ce2,
        int* __restrict__ idx_i, float* __restrict__ idx_f,
        int* __restrict__ hist, float* __restrict__ loss_s,
        int* __restrict__ nflag, int* __restrict__ flagged) {
    __shared__ unsigned short sA[2 * 32 * APAD];
    __shared__ unsigned short sB[2 * 256 * APAD];
    int t = threadIdx.x;
    int px0 = blockIdx.x * 32;
    int lane = t & 63, w = t >> 6;
    int m = lane & 15, quad = lane >> 4;
    f32x4 acc[2][4];
    #pragma unroll
    for (int pt = 0; pt < 2; pt++)
        #pragma unroll
        for (int ct = 0; ct < 4; ct++) acc[pt][ct] = (f32x4){0.f, 0.f, 0.f, 0.f};

    int apx = t >> 3, ak = (t & 7) * 4;
    int bc = t >> 2, bk = (t & 3) * 8;
    const size_t arow = ((size_t)(px0 + apx)) << 10;

    for (int kk = 0; kk < EDIM; kk += 32) {
        uint2 av0 = *(const uint2*)(zh + arow + kk + ak);
        uint2 av1 = *(const uint2*)(zl + arow + kk + ak);
        uint4 bv0[4], bv1[4];
        #pragma unroll
        for (int r = 0; r < 4; r++) {
            bv0[r] = *(const uint4*)(eh + (((size_t)(bc + 64 * r)) << 10) + kk + bk);
            bv1[r] = *(const uint4*)(el + (((size_t)(bc + 64 * r)) << 10) + kk + bk);
        }
        __syncthreads();   // all waves done reading LDS from previous iter
        *(uint2*)(sA + apx * APAD + ak) = av0;
        *(uint2*)(sA + 32 * APAD + apx * APAD + ak) = av1;
        #pragma unroll
        for (int r = 0; r < 4; r++) {
            *(uint4*)(sB + (bc + 64 * r) * APAD + bk) = bv0[r];
            *(uint4*)(sB + 256 * APAD + (bc + 64 * r) * APAD + bk) = bv1[r];
        }
        __syncthreads();
        short8 ah0 = *(const short8*)(sA + m * APAD + quad * 8);
        short8 ah1 = *(const short8*)(sA + (16 + m) * APAD + quad * 8);
        short8 al0 = *(const short8*)(sA + 32 * APAD + m * APAD + quad * 8);
        short8 al1 = *(const short8*)(sA + 32 * APAD + (16 + m) * APAD + quad * 8);
        #pragma unroll
        for (int ct = 0; ct < 4; ct++) {
            int row = w * 64 + ct * 16 + m;
            short8 bh = *(const short8*)(sB + row * APAD + quad * 8);
            short8 bl = *(const short8*)(sB + 256 * APAD + row * APAD + quad * 8);
            acc[0][ct] = __builtin_amdgcn_mfma_f32_16x16x32_bf16(ah0, bh, acc[0][ct], 0, 0, 0);
            acc[0][ct] = __builtin_amdgcn_mfma_f32_16x16x32_bf16(ah0, bl, acc[0][ct], 0, 0, 0);
            acc[0][ct] = __builtin_amdgcn_mfma_f32_16x16x32_bf16(al0, bh, acc[0][ct], 0, 0, 0);
            acc[1][ct] = __builtin_amdgcn_mfma_f32_16x16x32_bf16(ah1, bh, acc[1][ct], 0, 0, 0);
            acc[1][ct] = __builtin_amdgcn_mfma_f32_16x16x32_bf16(ah1, bl, acc[1][ct], 0, 0, 0);
            acc[1][ct] = __builtin_amdgcn_mfma_f32_16x16x32_bf16(al1, bh, acc[1][ct], 0, 0, 0);
        }
    }
    // ----- epilogue: per-pixel (best, idx, second-best) -----
    float c2[4];
    #pragma unroll
    for (int ct = 0; ct < 4; ct++) c2[ct] = ce2[w * 64 + ct * 16 + m];
    __syncthreads();
    float* red = (float*)sA;   // [4 waves][32 px][v1,i1,v2] + [32] partial sums
    #pragma unroll
    for (int pt = 0; pt < 2; pt++) {
        #pragma unroll
        for (int r = 0; r < 4; r++) {
            float v1 = 3.4e38f, v2 = 3.4e38f; int i1 = 0;
            #pragma unroll
            for (int ct = 0; ct < 4; ct++) {
                float sv = c2[ct] - acc[pt][ct][r];
                int code = w * 64 + ct * 16 + m;
                if (sv < v1 || (sv == v1 && code < i1)) { v2 = v1; v1 = sv; i1 = code; }
                else v2 = fminf(v2, sv);
            }
            #pragma unroll
            for (int msk = 1; msk < 16; msk <<= 1) {
                float ov1 = __shfl_xor(v1, msk, 64);
                int   oi1 = __shfl_xor(i1, msk, 64);
                float ov2 = __shfl_xor(v2, msk, 64);
                float nv2 = fminf(fminf(v2, ov2), fmaxf(v1, ov1));
                if (ov1 < v1 || (ov1 == v1 && oi1 < i1)) { v1 = ov1; i1 = oi1; }
                v2 = nv2;
            }
            if (m == 0) {
                int pxl = pt * 16 + quad * 4 + r;
                int bidx = (w * 32 + pxl) * 3;
                red[bidx] = v1; ((int*)red)[bidx + 1] = i1; red[bidx + 2] = v2;
            }
        }
    }
    __syncthreads();
    if (t < 32) {
        int pxl = t;
        int bidx = pxl * 3;
        float v1 = red[bidx]; int i1 = ((int*)red)[bidx + 1]; float v2 = red[bidx + 2];
        #pragma unroll
        for (int ww = 1; ww < 4; ww++) {
            int ob = (ww * 32 + pxl) * 3;
            float ov1 = red[ob]; int oi1 = ((int*)red)[ob + 1]; float ov2 = red[ob + 2];
            float nv2 = fminf(fminf(v2, ov2), fmaxf(v1, ov1));
            if (ov1 < v1 || (ov1 == v1 && oi1 < i1)) { v1 = ov1; i1 = oi1; }
            v2 = nv2;
        }
        int n = px0 + pxl;
        idx_i[n] = i1;
        idx_f[n] = (float)i1;
        atomicAdd(&hist[i1], 1);
        if (v2 - v1 < DELTA) {
            int pos = atomicAdd(nflag, 1);
            if (pos < MAXF) flagged[pos] = n;
        }
        red[384 + pxl] = v1;
    }
    __syncthreads();
    if (t == 0) {
        float sm = 0.f;
        for (int i2 = 0; i2 < 32; i2++) sm += red[384 + i2];
        atomicAdd(loss_s, sm);
    }
}

// ---------------- exact fp32 re-argmin for tie-flagged pixels --------------
__global__ __launch_bounds__(256) void k_cleanup(const float* __restrict__ z,
        const float* __restrict__ emb, const float* __restrict__ ce2,
        const int* __restrict__ nflag, const int* __restrict__ flagged,
        int* __restrict__ idx_i, float* __restrict__ idx_f, int* __restrict__ hist) {
    __shared__ float rv[4];
    __shared__ int ri[4];
    int t = threadIdx.x;
    int nf = *nflag; if (nf > MAXF) nf = MAXF;
    const float* er = emb + (size_t)t * EDIM;
    for (int i = blockIdx.x; i < nf; i += gridDim.x) {
        int px = flagged[i];
        int b = px >> 10, p = px & 1023;
        const float* zb = z + (((size_t)b) << 20) + p;
        float dot = 0.f;
        for (int c = 0; c < EDIM; c += 4) {
            float4 ev = *(const float4*)(er + c);
            dot += ev.x * zb[((size_t)(c + 0)) << 10]
                 + ev.y * zb[((size_t)(c + 1)) << 10]
                 + ev.z * zb[((size_t)(c + 2)) << 10]
                 + ev.w * zb[((size_t)(c + 3)) << 10];
        }
        float sv = ce2[t] - dot;
        int bi = t;
        #pragma unroll
        for (int msk = 1; msk < 64; msk <<= 1) {
            float ov = __shfl_xor(sv, msk, 64);
            int oi = __shfl_xor(bi, msk, 64);
            if (ov < sv || (ov == sv && oi < bi)) { sv = ov; bi = oi; }
        }
        if ((t & 63) == 0) { rv[t >> 6] = sv; ri[t >> 6] = bi; }
        __syncthreads();
        if (t == 0) {
            float v = rv[0]; int ix = ri[0];
            for (int ww = 1; ww < 4; ww++)
                if (rv[ww] < v || (rv[ww] == v && ri[ww] < ix)) { v = rv[ww]; ix = ri[ww]; }
            int old = idx_i[px];
            if (ix != old) {
                idx_i[px] = ix; idx_f[px] = (float)ix;
                atomicAdd(&hist[ix], 1); atomicSub(&hist[old], 1);
            }
        }
        __syncthreads();
    }
}

// ---------------- round-1 fp32 argmin (fallback only) ----------------------
__global__ __launch_bounds__(256) void k_argmin(const float* __restrict__ z,
                                                const float* __restrict__ emb,
                                                const float* __restrict__ ce2,
                                                int* __restrict__ idx_i,
                                                float* __restrict__ idx_f,
                                                int* __restrict__ hist,
                                                float* __restrict__ loss_acc) {
    __shared__ float zt[32 * 64];
    __shared__ float et[256 * 34];
    __shared__ float znorm_s[64];
    int t = threadIdx.x;
    int n0 = blockIdx.x * 64;
    int b = n0 >> 10;
    int p0 = n0 & 1023;
    const float* zb = z + (size_t)b * EDIM * HW;
    int tc = t & 31, tp = t >> 5;
    float acc[8][8] = {};
    float znorm = 0.f;
    for (int kk = 0; kk < EDIM; kk += 32) {
        #pragma unroll
        for (int i = 0; i < 16; i++) {
            int q = t + 256 * i;
            int code = q >> 4, k2 = q & 15;
            float2 v = *(const float2*)(emb + (size_t)code * EDIM + kk + k2 * 2);
            *(float2*)(et + code * 34 + k2 * 2) = v;
        }
        #pragma unroll
        for (int i = 0; i < 4; i++) {
            int q = t + 256 * i;
            int k = q >> 5, p2 = q & 31;
            float2 v = *(const float2*)(zb + (size_t)(kk + k) * HW + p0 + p2 * 2);
            *(float2*)(zt + k * 64 + p2 * 2) = v;
        }
        __syncthreads();
        if (t < 64) {
            #pragma unroll
            for (int k = 0; k < 32; k++) { float zz = zt[k * 64 + t]; znorm += zz * zz; }
        }
        #pragma unroll 4
        for (int k2 = 0; k2 < 16; k2++) {
            float2 ev[8], za[4], zb2[4];
            #pragma unroll
            for (int u = 0; u < 8; u++)
                ev[u] = *(float2*)(et + (tc + 32 * u) * 34 + k2 * 2);
            #pragma unroll
            for (int j = 0; j < 4; j++)
                za[j] = *(float2*)(zt + (2 * k2) * 64 + tp * 8 + 2 * j);
            #pragma unroll
            for (int j = 0; j < 4; j++)
                zb2[j] = *(float2*)(zt + (2 * k2 + 1) * 64 + tp * 8 + 2 * j);
            #pragma unroll
            for (int p = 0; p < 8; p++) {
                float z0 = (p & 1) ? za[p >> 1].y : za[p >> 1].x;
                float z1 = (p & 1) ? zb2[p >> 1].y : zb2[p >> 1].x;
                #pragma unroll
                for (int u = 0; u < 8; u++)
                    acc[p][u] += z0 * ev[u].x + z1 * ev[u].y;
            }
        }
        __syncthreads();
    }
    if (t < 64) znorm_s[t] = znorm;
    float minv[8];
    int mini[8];
    #pragma unroll
    for (int p = 0; p < 8; p++) { minv[p] = 3.4e38f; mini[p] = 0; }
    #pragma unroll
    for (int u = 0; u < 8; u++) {
        int code = tc + 32 * u;
        float cc2 = ce2[code];
        #pragma unroll
        for (int p = 0; p < 8; p++) {
            float s = cc2 - acc[p][u];
            if (s < minv[p] || (s == minv[p] && code < mini[p])) { minv[p] = s; mini[p] = code; }
        }
    }
    #pragma unroll
    for (int m = 1; m < 32; m <<= 1) {
        #pragma unroll
        for (int p = 0; p < 8; p++) {
            float ov = __shfl_xor(minv[p], m, 64);
            int oi = __shfl_xor(mini[p], m, 64);
            if (ov < minv[p] || (ov == minv[p] && oi < mini[p])) { minv[p] = ov; mini[p] = oi; }
        }
    }
    __syncthreads();
    if (tc == 0) {
        float dsum = 0.f;
        #pragma unroll
        for (int p = 0; p < 8; p++) {
            int lp = tp * 8 + p;
            int n = n0 + lp;
            idx_i[n] = mini[p];
            idx_f[n] = (float)mini[p];
            dsum += znorm_s[lp] + 2.f * minv[p];
            atomicAdd(&hist[mini[p]], 1);
        }
        atomicAdd(loss_acc, dsum);
    }
}

// ---------------- out[b][o][p] = T[o][idx[b][p]] + bias[o] -----------------
__global__ __launch_bounds__(256) void k_scatter(const float* __restrict__ T,
                                                 const float* __restrict__ bias,
                                                 const int* __restrict__ idx,
                                                 float* __restrict__ out) {
    int t = threadIdx.x;
    int og = blockIdx.x;
    int b = blockIdx.y;
    int4 i4 = *(const int4*)(idx + b * HW + t * 4);
    #pragma unroll
    for (int j = 0; j < 4; j++) {
        int o = og * 4 + j;
        const float* Tr = T + (size_t)o * NE;
        float bb = bias[o];
        float4 r;
        r.x = Tr[i4.x] + bb;
        r.y = Tr[i4.y] + bb;
        r.z = Tr[i4.z] + bb;
        r.w = Tr[i4.w] + bb;
        *(float4*)(out + ((size_t)(b * EDIM + o) * HW) + t * 4) = r;
    }
}

// ---------------- finalize -------------------------------------------------
__global__ __launch_bounds__(256) void k_final_new(const int* __restrict__ hist,
                                                   const float* __restrict__ loss_s,
                                                   const float* __restrict__ zsq,
                                                   float* __restrict__ out) {
    __shared__ float red[4];
    int t = threadIdx.x;
    float em = (float)hist[t] * (1.0f / 16384.0f);
    float v = em * logf(em + 1e-10f);
    #pragma unroll
    for (int m = 32; m; m >>= 1) v += __shfl_down(v, m, 64);
    if ((t & 63) == 0) red[t >> 6] = v;
    __syncthreads();
    if (t == 0) {
        float s = red[0] + red[1] + red[2] + red[3];
        out[OUT_ELEMS] = (zsq[0] + 2.f * loss_s[0]) * 1.25f / 16777216.f;
        out[OUT_ELEMS + 1] = expf(-s);
    }
}

__global__ __launch_bounds__(256) void k_final_old(const int* __restrict__ hist,
                                                   const float* __restrict__ loss_acc,
                                                   float* __restrict__ out) {
    __shared__ float red[4];
    int t = threadIdx.x;
    float em = (float)hist[t] * (1.0f / 16384.0f);
    float v = em * logf(em + 1e-10f);
    #pragma unroll
    for (int m = 32; m; m >>= 1) v += __shfl_down(v, m, 64);
    if ((t & 63) == 0) red[t >> 6] = v;
    __syncthreads();
    if (t == 0) {
        float s = red[0] + red[1] + red[2] + red[3];
        out[OUT_ELEMS] = loss_acc[0] * 1.25f / 16777216.f;
        out[OUT_ELEMS + 1] = expf(-s);
    }
}

extern "C" void kernel_launch(void* const* d_in, const int* in_sizes, int n_in,
                              void* d_out, int out_size, void* d_ws, size_t ws_size,
                              hipStream_t stream) {
    (void)in_sizes; (void)n_in; (void)out_size;
    const float* z      = (const float*)d_in[0];
    const float* emb    = (const float*)d_in[1];
    const float* conv_w = (const float*)d_in[2];
    const float* conv_b = (const float*)d_in[3];
    float* out = (float*)d_out;

    if (ws_size >= WF_NEED) {
        // ---- fast path: MFMA bf16x3 distance GEMM, zh/zl scratch in d_out ----
        float* ce2      = (float*)((char*)d_ws + WF_CE2);
        int*   hist     = (int*)((char*)d_ws + WF_HIST);
        float* loss_s   = (float*)((char*)d_ws + WF_LOSS);
        float* zsq      = (float*)((char*)d_ws + WF_ZSQ);
        int*   nflag    = (int*)((char*)d_ws + WF_NFLAG);
        int*   flagged  = (int*)((char*)d_ws + WF_FLAG);
        int*   idx_i    = (int*)((char*)d_ws + WF_IDX);
        float* T        = (float*)((char*)d_ws + WF_T);
        unsigned short* eh = (unsigned short*)((char*)d_ws + WF_EH);
        unsigned short* el = (unsigned short*)((char*)d_ws + WF_EL);
        unsigned short* zh = (unsigned short*)out;                 // 33.5 MB
        unsigned short* zl = zh + (size_t)NPIX * EDIM;             // 33.5 MB
        float* idx_f = out + OUT_ELEMS + 2;

        hipMemsetAsync(d_ws, 0, WF_MEMSET, stream);
        k_prep_e<<<256, 256, 0, stream>>>(emb, eh, el);
        k_prep_z<<<4096, 256, 0, stream>>>(z, zh, zl, zsq);
        k_norms<<<NE, 64, 0, stream>>>(emb, ce2);
        k_wT<<<dim3(4, 16, 4), 256, 0, stream>>>(conv_w, emb, T);
        k_dist<<<512, 256, 0, stream>>>(zh, zl, eh, el, ce2, idx_i, idx_f,
                                        hist, loss_s, nflag, flagged);
        k_cleanup<<<64, 256, 0, stream>>>(z, emb, ce2, nflag, flagged,
                                          idx_i, idx_f, hist);
        k_scatter<<<dim3(256, 16), 256, 0, stream>>>(T, conv_b, idx_i, out);
        k_final_new<<<1, 256, 0, stream>>>(hist, loss_s, zsq, out);
    } else {
        // ---- fallback: round-1 fp32 path ----
        float* ce2      = (float*)((char*)d_ws + WO_CE2);
        int*   hist     = (int*)((char*)d_ws + WO_HIST);
        float* loss_acc = (float*)((char*)d_ws + WO_LOSS);
        int*   idx_i    = (int*)((char*)d_ws + WO_IDX);
        float* T        = (float*)((char*)d_ws + WO_T);
        float* idx_f = out + OUT_ELEMS + 2;

        hipMemsetAsync(d_ws, 0, WO_TOTAL, stream);
        k_norms<<<NE, 64, 0, stream>>>(emb, ce2);
        k_wT<<<dim3(4, 16, 4), 256, 0, stream>>>(conv_w, emb, T);
        k_argmin<<<256, 256, 0, stream>>>(z, emb, ce2, idx_i, idx_f, hist, loss_acc);
        k_scatter<<<dim3(256, 16), 256, 0, stream>>>(T, conv_b, idx_i, out);
        k_final_old<<<1, 256, 0, stream>>>(hist, loss_acc, out);
    }
}

// Round 3
// 417.590 us; speedup vs baseline: 2.2745x; 2.2745x over previous
//
#include <hip/hip_runtime.h>
#include <math.h>

#define NE 256
#define EDIM 1024
#define HW 1024
#define NPIX 16384
#define OUT_ELEMS 16777216

typedef short short8 __attribute__((ext_vector_type(8)));
typedef float f32x4 __attribute__((ext_vector_type(4)));

// ---------------- fast-path workspace layout (bytes) ----------------
#define WF_CE2    0          // float[256]
#define WF_HIST   1024       // int[256]
#define WF_LOSS   2048       // float
#define WF_ZSQ    2052       // float
#define WF_NFLAG  2056       // int
#define WF_FLAG   4096       // int[4096]
#define WF_IDX    20480      // int[16384]
#define WF_T      86016      // float[1024*256]
#define WF_EH     1134592    // ushort[256*1024]
#define WF_EL     1658880    // ushort[256*1024]
#define WF_NEED   2183168
#define WF_MEMSET 1134592    // control + flagged + idx + T
#define MAXF 4096
#define DELTA 0.05f          // tie-guard; bf16x3 distance error bound ~5e-4 -> 100x margin

// ---------------- fallback (round-1) workspace layout ----------------
#define WO_CE2  0
#define WO_HIST 1024
#define WO_LOSS 2048
#define WO_IDX  4096
#define WO_T    69632
#define WO_TOTAL 1118208

#define APAD 40   // LDS row stride in bf16 elems: 80 B = 16B-aligned, ~2-way banks

__device__ __forceinline__ unsigned short f2bf(float f) {
    unsigned u = __float_as_uint(f);
    unsigned r = u + 0x7FFFu + ((u >> 16) & 1u);   // RNE
    return (unsigned short)(r >> 16);
}
__device__ __forceinline__ float bf2f(unsigned short h) {
    return __uint_as_float(((unsigned)h) << 16);
}

// ---------------- ce2[j] = 0.5*||emb_j||^2 (exact fp32) ----------------
__global__ __launch_bounds__(64) void k_norms(const float* __restrict__ emb,
                                              float* __restrict__ ce2) {
    int j = blockIdx.x;
    int lane = threadIdx.x;
    const float* row = emb + (size_t)j * EDIM;
    float s = 0.f;
    #pragma unroll
    for (int i = 0; i < EDIM / 64; i++) {
        float v = row[lane + 64 * i];
        s += v * v;
    }
    #pragma unroll
    for (int m = 32; m; m >>= 1) s += __shfl_down(s, m, 64);
    if (lane == 0) ce2[j] = 0.5f * s;
}

// ---------------- T[o][j] = sum_c w[o][c]*emb[j][c] (split-K, atomics) ----
__global__ __launch_bounds__(256) void k_wT(const float* __restrict__ w,
                                            const float* __restrict__ emb,
                                            float* __restrict__ T) {
    __shared__ float wt[64 * 17];
    __shared__ float et[64 * 17];
    int t = threadIdx.x;
    int j0 = blockIdx.x * 64;
    int o0 = blockIdx.y * 64;
    int kb = blockIdx.z * 256;
    int to = t & 15, tj = t >> 4;
    float acc[4][4] = {};
    int lr = t >> 2, lk = (t & 3) * 4;
    for (int kk = kb; kk < kb + 256; kk += 16) {
        float4 wv = *(const float4*)(w + (size_t)(o0 + lr) * EDIM + kk + lk);
        float4 ev = *(const float4*)(emb + (size_t)(j0 + lr) * EDIM + kk + lk);
        __syncthreads();
        wt[lr * 17 + lk + 0] = wv.x; wt[lr * 17 + lk + 1] = wv.y;
        wt[lr * 17 + lk + 2] = wv.z; wt[lr * 17 + lk + 3] = wv.w;
        et[lr * 17 + lk + 0] = ev.x; et[lr * 17 + lk + 1] = ev.y;
        et[lr * 17 + lk + 2] = ev.z; et[lr * 17 + lk + 3] = ev.w;
        __syncthreads();
        #pragma unroll
        for (int k = 0; k < 16; k++) {
            float a[4], b[4];
            #pragma unroll
            for (int i = 0; i < 4; i++) a[i] = wt[(to * 4 + i) * 17 + k];
            #pragma unroll
            for (int i = 0; i < 4; i++) b[i] = et[(tj * 4 + i) * 17 + k];
            #pragma unroll
            for (int i = 0; i < 4; i++)
                #pragma unroll
                for (int jx = 0; jx < 4; jx++) acc[i][jx] += a[i] * b[jx];
        }
    }
    #pragma unroll
    for (int i = 0; i < 4; i++)
        #pragma unroll
        for (int jx = 0; jx < 4; jx++)
            atomicAdd(&T[(size_t)(o0 + to * 4 + i) * NE + j0 + tj * 4 + jx],
                      acc[i][jx]);
}

// ---------------- prep: emb fp32 -> eh/el bf16 [code][k] -------------------
__global__ __launch_bounds__(256) void k_prep_e(const float* __restrict__ emb,
                                                unsigned short* __restrict__ eh,
                                                unsigned short* __restrict__ el) {
    int i = (blockIdx.x * 256 + threadIdx.x) * 4;
    float4 v = *(const float4*)(emb + i);
    unsigned short h0 = f2bf(v.x), h1 = f2bf(v.y), h2 = f2bf(v.z), h3 = f2bf(v.w);
    unsigned short l0 = f2bf(v.x - bf2f(h0)), l1 = f2bf(v.y - bf2f(h1));
    unsigned short l2 = f2bf(v.z - bf2f(h2)), l3 = f2bf(v.w - bf2f(h3));
    uint2 hp, lp;
    hp.x = (unsigned)h0 | ((unsigned)h1 << 16); hp.y = (unsigned)h2 | ((unsigned)h3 << 16);
    lp.x = (unsigned)l0 | ((unsigned)l1 << 16); lp.y = (unsigned)l2 | ((unsigned)l3 << 16);
    *(uint2*)(eh + i) = hp;
    *(uint2*)(el + i) = lp;
}

// ---------------- prep: z [b][c][p] -> zh/zl bf16 [px][k] + sum(z^2) -------
__global__ __launch_bounds__(256) void k_prep_z(const float* __restrict__ z,
                                                unsigned short* __restrict__ zh,
                                                unsigned short* __restrict__ zl,
                                                float* __restrict__ zsq_acc) {
    __shared__ float tile[64 * 69];
    __shared__ float sw[4];
    int t = threadIdx.x;
    int blk = blockIdx.x;                  // 4096 = 16b * 16 ctile * 16 ptile
    int b = blk >> 8;
    int ct0 = ((blk >> 4) & 15) * 64;
    int pt0 = (blk & 15) * 64;
    float s = 0.f;
    #pragma unroll
    for (int r = 0; r < 4; r++) {
        int c = r * 16 + (t >> 4);
        int px4 = (t & 15) * 4;
        float4 v = *(const float4*)(z + (((size_t)(b * 1024 + ct0 + c)) << 10) + pt0 + px4);
        *(float4*)(tile + c * 69 + px4) = v;
        s += v.x * v.x + v.y * v.y + v.z * v.z + v.w * v.w;
    }
    __syncthreads();
    int px = t >> 2, cg = t & 3;
    unsigned int hu[8], lu[8];
    #pragma unroll
    for (int i = 0; i < 8; i++) {
        float f0 = tile[(cg * 16 + 2 * i) * 69 + px];
        float f1 = tile[(cg * 16 + 2 * i + 1) * 69 + px];
        unsigned short h0 = f2bf(f0), h1 = f2bf(f1);
        unsigned short l0 = f2bf(f0 - bf2f(h0)), l1 = f2bf(f1 - bf2f(h1));
        hu[i] = (unsigned)h0 | ((unsigned)h1 << 16);
        lu[i] = (unsigned)l0 | ((unsigned)l1 << 16);
    }
    size_t base = (((size_t)(b * 1024 + pt0 + px)) << 10) + ct0 + cg * 16;
    *(uint4*)(zh + base)     = make_uint4(hu[0], hu[1], hu[2], hu[3]);
    *(uint4*)(zh + base + 8) = make_uint4(hu[4], hu[5], hu[6], hu[7]);
    *(uint4*)(zl + base)     = make_uint4(lu[0], lu[1], lu[2], lu[3]);
    *(uint4*)(zl + base + 8) = make_uint4(lu[4], lu[5], lu[6], lu[7]);
    #pragma unroll
    for (int m = 32; m; m >>= 1) s += __shfl_down(s, m, 64);
    if ((t & 63) == 0) sw[t >> 6] = s;
    __syncthreads();
    if (t == 0) atomicAdd(zsq_acc, sw[0] + sw[1] + sw[2] + sw[3]);
}

// ---------------- MFMA distance GEMM + argmin + tie-flagging ---------------
// grid 512 (32 px each), 256 thr (4 waves). Wave w: codes [w*64, w*64+64).
// bf16x3: S = zh*eh + zh*el + zl*eh. score s = 0.5||e||^2 - S; flag gap<DELTA.
__global__ __launch_bounds__(256) void k_dist(
        const unsigned short* __restrict__ zh, const unsigned short* __restrict__ zl,
        const unsigned short* __restrict__ eh, const unsigned short* __restrict__ el,
        const float* __restrict__ ce2,
        int* __restrict__ idx_i, float* __restrict__ idx_f,
        int* __restrict__ hist, float* __restrict__ loss_s,
        int* __restrict__ nflag, int* __restrict__ flagged) {
    __shared__ unsigned short sA[2 * 32 * APAD];
    __shared__ unsigned short sB[2 * 256 * APAD];
    int t = threadIdx.x;
    int px0 = blockIdx.x * 32;
    int lane = t & 63, w = t >> 6;
    int m = lane & 15, quad = lane >> 4;
    f32x4 acc[2][4];
    #pragma unroll
    for (int pt = 0; pt < 2; pt++)
        #pragma unroll
        for (int ct = 0; ct < 4; ct++) acc[pt][ct] = (f32x4){0.f, 0.f, 0.f, 0.f};

    int apx = t >> 3, ak = (t & 7) * 4;
    int bc = t >> 2, bk = (t & 3) * 8;
    const size_t arow = ((size_t)(px0 + apx)) << 10;

    for (int kk = 0; kk < EDIM; kk += 32) {
        uint2 av0 = *(const uint2*)(zh + arow + kk + ak);
        uint2 av1 = *(const uint2*)(zl + arow + kk + ak);
        uint4 bv0[4], bv1[4];
        #pragma unroll
        for (int r = 0; r < 4; r++) {
            bv0[r] = *(const uint4*)(eh + (((size_t)(bc + 64 * r)) << 10) + kk + bk);
            bv1[r] = *(const uint4*)(el + (((size_t)(bc + 64 * r)) << 10) + kk + bk);
        }
        __syncthreads();   // all waves done reading LDS from previous iter
        *(uint2*)(sA + apx * APAD + ak) = av0;
        *(uint2*)(sA + 32 * APAD + apx * APAD + ak) = av1;
        #pragma unroll
        for (int r = 0; r < 4; r++) {
            *(uint4*)(sB + (bc + 64 * r) * APAD + bk) = bv0[r];
            *(uint4*)(sB + 256 * APAD + (bc + 64 * r) * APAD + bk) = bv1[r];
        }
        __syncthreads();
        short8 ah0 = *(const short8*)(sA + m * APAD + quad * 8);
        short8 ah1 = *(const short8*)(sA + (16 + m) * APAD + quad * 8);
        short8 al0 = *(const short8*)(sA + 32 * APAD + m * APAD + quad * 8);
        short8 al1 = *(const short8*)(sA + 32 * APAD + (16 + m) * APAD + quad * 8);
        #pragma unroll
        for (int ct = 0; ct < 4; ct++) {
            int row = w * 64 + ct * 16 + m;
            short8 bh = *(const short8*)(sB + row * APAD + quad * 8);
            short8 bl = *(const short8*)(sB + 256 * APAD + row * APAD + quad * 8);
            acc[0][ct] = __builtin_amdgcn_mfma_f32_16x16x32_bf16(ah0, bh, acc[0][ct], 0, 0, 0);
            acc[0][ct] = __builtin_amdgcn_mfma_f32_16x16x32_bf16(ah0, bl, acc[0][ct], 0, 0, 0);
            acc[0][ct] = __builtin_amdgcn_mfma_f32_16x16x32_bf16(al0, bh, acc[0][ct], 0, 0, 0);
            acc[1][ct] = __builtin_amdgcn_mfma_f32_16x16x32_bf16(ah1, bh, acc[1][ct], 0, 0, 0);
            acc[1][ct] = __builtin_amdgcn_mfma_f32_16x16x32_bf16(ah1, bl, acc[1][ct], 0, 0, 0);
            acc[1][ct] = __builtin_amdgcn_mfma_f32_16x16x32_bf16(al1, bh, acc[1][ct], 0, 0, 0);
        }
    }
    // ----- epilogue: per-pixel (best, idx, second-best) -----
    float c2[4];
    #pragma unroll
    for (int ct = 0; ct < 4; ct++) c2[ct] = ce2[w * 64 + ct * 16 + m];
    __syncthreads();
    float* red = (float*)sA;   // [4 waves][32 px][v1,i1,v2] + [32] partial sums
    #pragma unroll
    for (int pt = 0; pt < 2; pt++) {
        #pragma unroll
        for (int r = 0; r < 4; r++) {
            float v1 = 3.4e38f, v2 = 3.4e38f; int i1 = 0;
            #pragma unroll
            for (int ct = 0; ct < 4; ct++) {
                float sv = c2[ct] - acc[pt][ct][r];
                int code = w * 64 + ct * 16 + m;
                if (sv < v1 || (sv == v1 && code < i1)) { v2 = v1; v1 = sv; i1 = code; }
                else v2 = fminf(v2, sv);
            }
            #pragma unroll
            for (int msk = 1; msk < 16; msk <<= 1) {
                float ov1 = __shfl_xor(v1, msk, 64);
                int   oi1 = __shfl_xor(i1, msk, 64);
                float ov2 = __shfl_xor(v2, msk, 64);
                float nv2 = fminf(fminf(v2, ov2), fmaxf(v1, ov1));
                if (ov1 < v1 || (ov1 == v1 && oi1 < i1)) { v1 = ov1; i1 = oi1; }
                v2 = nv2;
            }
            if (m == 0) {
                int pxl = pt * 16 + quad * 4 + r;
                int bidx = (w * 32 + pxl) * 3;
                red[bidx] = v1; ((int*)red)[bidx + 1] = i1; red[bidx + 2] = v2;
            }
        }
    }
    __syncthreads();
    if (t < 32) {
        int pxl = t;
        int bidx = pxl * 3;
        float v1 = red[bidx]; int i1 = ((int*)red)[bidx + 1]; float v2 = red[bidx + 2];
        #pragma unroll
        for (int ww = 1; ww < 4; ww++) {
            int ob = (ww * 32 + pxl) * 3;
            float ov1 = red[ob]; int oi1 = ((int*)red)[ob + 1]; float ov2 = red[ob + 2];
            float nv2 = fminf(fminf(v2, ov2), fmaxf(v1, ov1));
            if (ov1 < v1 || (ov1 == v1 && oi1 < i1)) { v1 = ov1; i1 = oi1; }
            v2 = nv2;
        }
        int n = px0 + pxl;
        idx_i[n] = i1;
        idx_f[n] = (float)i1;
        atomicAdd(&hist[i1], 1);
        if (v2 - v1 < DELTA) {
            int pos = atomicAdd(nflag, 1);
            if (pos < MAXF) flagged[pos] = n;
        }
        red[384 + pxl] = v1;
    }
    __syncthreads();
    if (t == 0) {
        float sm = 0.f;
        for (int i2 = 0; i2 < 32; i2++) sm += red[384 + i2];
        atomicAdd(loss_s, sm);
    }
}

// ---------------- exact fp32 re-argmin for tie-flagged pixels --------------
// One block per flagged pixel (grid-stride). Cooperative z-column gather into
// LDS (1024 independent loads in flight), then thread t = code t dots against
// its contiguous L2-resident emb row. LDS z reads are wave-broadcast (free).
__global__ __launch_bounds__(256) void k_cleanup(const float* __restrict__ z,
        const float* __restrict__ emb, const float* __restrict__ ce2,
        const int* __restrict__ nflag, const int* __restrict__ flagged,
        int* __restrict__ idx_i, float* __restrict__ idx_f, int* __restrict__ hist) {
    __shared__ float zs[1024];
    __shared__ float rv[4];
    __shared__ int ri[4];
    int t = threadIdx.x;
    int nf = *nflag; if (nf > MAXF) nf = MAXF;
    const float* er = emb + (size_t)t * EDIM;
    for (int i = blockIdx.x; i < nf; i += gridDim.x) {
        int px = flagged[i];
        int b = px >> 10, p = px & 1023;
        const float* zb = z + (((size_t)b) << 20) + p;
        #pragma unroll
        for (int r = 0; r < 4; r++) {
            int c = t + 256 * r;
            zs[c] = zb[((size_t)c) << 10];
        }
        __syncthreads();
        float d0 = 0.f, d1 = 0.f, d2 = 0.f, d3 = 0.f;
        #pragma unroll 4
        for (int c = 0; c < EDIM; c += 16) {
            float4 e0 = *(const float4*)(er + c);
            float4 e1 = *(const float4*)(er + c + 4);
            float4 e2 = *(const float4*)(er + c + 8);
            float4 e3 = *(const float4*)(er + c + 12);
            d0 += e0.x * zs[c]      + e0.y * zs[c + 1]  + e0.z * zs[c + 2]  + e0.w * zs[c + 3];
            d1 += e1.x * zs[c + 4]  + e1.y * zs[c + 5]  + e1.z * zs[c + 6]  + e1.w * zs[c + 7];
            d2 += e2.x * zs[c + 8]  + e2.y * zs[c + 9]  + e2.z * zs[c + 10] + e2.w * zs[c + 11];
            d3 += e3.x * zs[c + 12] + e3.y * zs[c + 13] + e3.z * zs[c + 14] + e3.w * zs[c + 15];
        }
        float sv = ce2[t] - ((d0 + d1) + (d2 + d3));
        int bi = t;
        #pragma unroll
        for (int msk = 1; msk < 64; msk <<= 1) {
            float ov = __shfl_xor(sv, msk, 64);
            int oi = __shfl_xor(bi, msk, 64);
            if (ov < sv || (ov == sv && oi < bi)) { sv = ov; bi = oi; }
        }
        if ((t & 63) == 0) { rv[t >> 6] = sv; ri[t >> 6] = bi; }
        __syncthreads();
        if (t == 0) {
            float v = rv[0]; int ix = ri[0];
            for (int ww = 1; ww < 4; ww++)
                if (rv[ww] < v || (rv[ww] == v && ri[ww] < ix)) { v = rv[ww]; ix = ri[ww]; }
            int old = idx_i[px];
            if (ix != old) {
                idx_i[px] = ix; idx_f[px] = (float)ix;
                atomicAdd(&hist[ix], 1); atomicSub(&hist[old], 1);
            }
        }
        __syncthreads();   // protect zs before next pixel overwrites it
    }
}

// ---------------- round-1 fp32 argmin (fallback only) ----------------------
__global__ __launch_bounds__(256) void k_argmin(const float* __restrict__ z,
                                                const float* __restrict__ emb,
                                                const float* __restrict__ ce2,
                                                int* __restrict__ idx_i,
                                                float* __restrict__ idx_f,
                                                int* __restrict__ hist,
                                                float* __restrict__ loss_acc) {
    __shared__ float zt[32 * 64];
    __shared__ float et[256 * 34];
    __shared__ float znorm_s[64];
    int t = threadIdx.x;
    int n0 = blockIdx.x * 64;
    int b = n0 >> 10;
    int p0 = n0 & 1023;
    const float* zb = z + (size_t)b * EDIM * HW;
    int tc = t & 31, tp = t >> 5;
    float acc[8][8] = {};
    float znorm = 0.f;
    for (int kk = 0; kk < EDIM; kk += 32) {
        #pragma unroll
        for (int i = 0; i < 16; i++) {
            int q = t + 256 * i;
            int code = q >> 4, k2 = q & 15;
            float2 v = *(const float2*)(emb + (size_t)code * EDIM + kk + k2 * 2);
            *(float2*)(et + code * 34 + k2 * 2) = v;
        }
        #pragma unroll
        for (int i = 0; i < 4; i++) {
            int q = t + 256 * i;
            int k = q >> 5, p2 = q & 31;
            float2 v = *(const float2*)(zb + (size_t)(kk + k) * HW + p0 + p2 * 2);
            *(float2*)(zt + k * 64 + p2 * 2) = v;
        }
        __syncthreads();
        if (t < 64) {
            #pragma unroll
            for (int k = 0; k < 32; k++) { float zz = zt[k * 64 + t]; znorm += zz * zz; }
        }
        #pragma unroll 4
        for (int k2 = 0; k2 < 16; k2++) {
            float2 ev[8], za[4], zb2[4];
            #pragma unroll
            for (int u = 0; u < 8; u++)
                ev[u] = *(float2*)(et + (tc + 32 * u) * 34 + k2 * 2);
            #pragma unroll
            for (int j = 0; j < 4; j++)
                za[j] = *(float2*)(zt + (2 * k2) * 64 + tp * 8 + 2 * j);
            #pragma unroll
            for (int j = 0; j < 4; j++)
                zb2[j] = *(float2*)(zt + (2 * k2 + 1) * 64 + tp * 8 + 2 * j);
            #pragma unroll
            for (int p = 0; p < 8; p++) {
                float z0 = (p & 1) ? za[p >> 1].y : za[p >> 1].x;
                float z1 = (p & 1) ? zb2[p >> 1].y : zb2[p >> 1].x;
                #pragma unroll
                for (int u = 0; u < 8; u++)
                    acc[p][u] += z0 * ev[u].x + z1 * ev[u].y;
            }
        }
        __syncthreads();
    }
    if (t < 64) znorm_s[t] = znorm;
    float minv[8];
    int mini[8];
    #pragma unroll
    for (int p = 0; p < 8; p++) { minv[p] = 3.4e38f; mini[p] = 0; }
    #pragma unroll
    for (int u = 0; u < 8; u++) {
        int code = tc + 32 * u;
        float cc2 = ce2[code];
        #pragma unroll
        for (int p = 0; p < 8; p++) {
            float s = cc2 - acc[p][u];
            if (s < minv[p] || (s == minv[p] && code < mini[p])) { minv[p] = s; mini[p] = code; }
        }
    }
    #pragma unroll
    for (int m = 1; m < 32; m <<= 1) {
        #pragma unroll
        for (int p = 0; p < 8; p++) {
            float ov = __shfl_xor(minv[p], m, 64);
            int oi = __shfl_xor(mini[p], m, 64);
            if (ov < minv[p] || (ov == minv[p] && oi < mini[p])) { minv[p] = ov; mini[p] = oi; }
        }
    }
    __syncthreads();
    if (tc == 0) {
        float dsum = 0.f;
        #pragma unroll
        for (int p = 0; p < 8; p++) {
            int lp = tp * 8 + p;
            int n = n0 + lp;
            idx_i[n] = mini[p];
            idx_f[n] = (float)mini[p];
            dsum += znorm_s[lp] + 2.f * minv[p];
            atomicAdd(&hist[mini[p]], 1);
        }
        atomicAdd(loss_acc, dsum);
    }
}

// ---------------- out[b][o][p] = T[o][idx[b][p]] + bias[o] -----------------
__global__ __launch_bounds__(256) void k_scatter(const float* __restrict__ T,
                                                 const float* __restrict__ bias,
                                                 const int* __restrict__ idx,
                                                 float* __restrict__ out) {
    int t = threadIdx.x;
    int og = blockIdx.x;
    int b = blockIdx.y;
    int4 i4 = *(const int4*)(idx + b * HW + t * 4);
    #pragma unroll
    for (int j = 0; j < 4; j++) {
        int o = og * 4 + j;
        const float* Tr = T + (size_t)o * NE;
        float bb = bias[o];
        float4 r;
        r.x = Tr[i4.x] + bb;
        r.y = Tr[i4.y] + bb;
        r.z = Tr[i4.z] + bb;
        r.w = Tr[i4.w] + bb;
        *(float4*)(out + ((size_t)(b * EDIM + o) * HW) + t * 4) = r;
    }
}

// ---------------- finalize -------------------------------------------------
__global__ __launch_bounds__(256) void k_final_new(const int* __restrict__ hist,
                                                   const float* __restrict__ loss_s,
                                                   const float* __restrict__ zsq,
                                                   float* __restrict__ out) {
    __shared__ float red[4];
    int t = threadIdx.x;
    float em = (float)hist[t] * (1.0f / 16384.0f);
    float v = em * logf(em + 1e-10f);
    #pragma unroll
    for (int m = 32; m; m >>= 1) v += __shfl_down(v, m, 64);
    if ((t & 63) == 0) red[t >> 6] = v;
    __syncthreads();
    if (t == 0) {
        float s = red[0] + red[1] + red[2] + red[3];
        out[OUT_ELEMS] = (zsq[0] + 2.f * loss_s[0]) * 1.25f / 16777216.f;
        out[OUT_ELEMS + 1] = expf(-s);
    }
}

__global__ __launch_bounds__(256) void k_final_old(const int* __restrict__ hist,
                                                   const float* __restrict__ loss_acc,
                                                   float* __restrict__ out) {
    __shared__ float red[4];
    int t = threadIdx.x;
    float em = (float)hist[t] * (1.0f / 16384.0f);
    float v = em * logf(em + 1e-10f);
    #pragma unroll
    for (int m = 32; m; m >>= 1) v += __shfl_down(v, m, 64);
    if ((t & 63) == 0) red[t >> 6] = v;
    __syncthreads();
    if (t == 0) {
        float s = red[0] + red[1] + red[2] + red[3];
        out[OUT_ELEMS] = loss_acc[0] * 1.25f / 16777216.f;
        out[OUT_ELEMS + 1] = expf(-s);
    }
}

extern "C" void kernel_launch(void* const* d_in, const int* in_sizes, int n_in,
                              void* d_out, int out_size, void* d_ws, size_t ws_size,
                              hipStream_t stream) {
    (void)in_sizes; (void)n_in; (void)out_size;
    const float* z      = (const float*)d_in[0];
    const float* emb    = (const float*)d_in[1];
    const float* conv_w = (const float*)d_in[2];
    const float* conv_b = (const float*)d_in[3];
    float* out = (float*)d_out;

    if (ws_size >= WF_NEED) {
        // ---- fast path: MFMA bf16x3 distance GEMM, zh/zl scratch in d_out ----
        float* ce2      = (float*)((char*)d_ws + WF_CE2);
        int*   hist     = (int*)((char*)d_ws + WF_HIST);
        float* loss_s   = (float*)((char*)d_ws + WF_LOSS);
        float* zsq      = (float*)((char*)d_ws + WF_ZSQ);
        int*   nflag    = (int*)((char*)d_ws + WF_NFLAG);
        int*   flagged  = (int*)((char*)d_ws + WF_FLAG);
        int*   idx_i    = (int*)((char*)d_ws + WF_IDX);
        float* T        = (float*)((char*)d_ws + WF_T);
        unsigned short* eh = (unsigned short*)((char*)d_ws + WF_EH);
        unsigned short* el = (unsigned short*)((char*)d_ws + WF_EL);
        unsigned short* zh = (unsigned short*)out;                 // 33.5 MB
        unsigned short* zl = zh + (size_t)NPIX * EDIM;             // 33.5 MB
        float* idx_f = out + OUT_ELEMS + 2;

        hipMemsetAsync(d_ws, 0, WF_MEMSET, stream);
        k_prep_e<<<256, 256, 0, stream>>>(emb, eh, el);
        k_prep_z<<<4096, 256, 0, stream>>>(z, zh, zl, zsq);
        k_norms<<<NE, 64, 0, stream>>>(emb, ce2);
        k_wT<<<dim3(4, 16, 4), 256, 0, stream>>>(conv_w, emb, T);
        k_dist<<<512, 256, 0, stream>>>(zh, zl, eh, el, ce2, idx_i, idx_f,
                                        hist, loss_s, nflag, flagged);
        k_cleanup<<<256, 256, 0, stream>>>(z, emb, ce2, nflag, flagged,
                                           idx_i, idx_f, hist);
        k_scatter<<<dim3(256, 16), 256, 0, stream>>>(T, conv_b, idx_i, out);
        k_final_new<<<1, 256, 0, stream>>>(hist, loss_s, zsq, out);
    } else {
        // ---- fallback: round-1 fp32 path ----
        float* ce2      = (float*)((char*)d_ws + WO_CE2);
        int*   hist     = (int*)((char*)d_ws + WO_HIST);
        float* loss_acc = (float*)((char*)d_ws + WO_LOSS);
        int*   idx_i    = (int*)((char*)d_ws + WO_IDX);
        float* T        = (float*)((char*)d_ws + WO_T);
        float* idx_f = out + OUT_ELEMS + 2;

        hipMemsetAsync(d_ws, 0, WO_TOTAL, stream);
        k_norms<<<NE, 64, 0, stream>>>(emb, ce2);
        k_wT<<<dim3(4, 16, 4), 256, 0, stream>>>(conv_w, emb, T);
        k_argmin<<<256, 256, 0, stream>>>(z, emb, ce2, idx_i, idx_f, hist, loss_acc);
        k_scatter<<<dim3(256, 16), 256, 0, stream>>>(T, conv_b, idx_i, out);
        k_final_old<<<1, 256, 0, stream>>>(hist, loss_acc, out);
    }
}

// Round 4
// 363.212 us; speedup vs baseline: 2.6150x; 1.1497x over previous
//
#include <hip/hip_runtime.h>
#include <math.h>

#define NE 256
#define EDIM 1024
#define HW 1024
#define NPIX 16384
#define OUT_ELEMS 16777216

typedef short short8 __attribute__((ext_vector_type(8)));
typedef float f32x4 __attribute__((ext_vector_type(4)));

// ---------------- fast-path workspace layout (bytes) ----------------
// [memset region: hist + ctrl + T]
#define WS_HIST   0          // int[256]
#define WS_LOSS   1024       // float
#define WS_ZSQ    1028       // float
#define WS_NFLAG  1032       // int
#define WS_T      4096       // float[1024*256] = 1 MB
#define WS_MEMSET 1052672
// [no-init region]
#define WS_CE2    1052672    // float[256]
#define WS_FLAG   1053696    // int[16384]
#define WS_IDX    1119232    // int[16384]
#define WS_EH     1184768    // ushort[256*1024] = 512 KB
#define WS_NEED   1709056

#define MAXF 16384           // can hold ALL pixels -> overflow can't drop any
#define DELTA 0.6f           // tie-guard; 1-pass bf16 score-diff sigma ~0.07 -> ~8.3 sigma

// ---------------- fallback (round-1) workspace layout ----------------
#define WO_CE2  0
#define WO_HIST 1024
#define WO_LOSS 2048
#define WO_IDX  4096
#define WO_T    69632
#define WO_TOTAL 1118208

__device__ __forceinline__ unsigned short f2bf(float f) {
    unsigned u = __float_as_uint(f);
    unsigned r = u + 0x7FFFu + ((u >> 16) & 1u);   // RNE
    return (unsigned short)(r >> 16);
}

// ---------------- ce2[j] = 0.5*||emb_j||^2 (exact fp32) ----------------
__global__ __launch_bounds__(64) void k_norms(const float* __restrict__ emb,
                                              float* __restrict__ ce2) {
    int j = blockIdx.x;
    int lane = threadIdx.x;
    const float* row = emb + (size_t)j * EDIM;
    float s = 0.f;
    #pragma unroll
    for (int i = 0; i < EDIM / 64; i++) {
        float v = row[lane + 64 * i];
        s += v * v;
    }
    #pragma unroll
    for (int m = 32; m; m >>= 1) s += __shfl_down(s, m, 64);
    if (lane == 0) ce2[j] = 0.5f * s;
}

// ---------------- T[o][j] = sum_c w[o][c]*emb[j][c] (split-K, atomics) ----
__global__ __launch_bounds__(256) void k_wT(const float* __restrict__ w,
                                            const float* __restrict__ emb,
                                            float* __restrict__ T) {
    __shared__ float wt[64 * 17];
    __shared__ float et[64 * 17];
    int t = threadIdx.x;
    int j0 = blockIdx.x * 64;
    int o0 = blockIdx.y * 64;
    int kb = blockIdx.z * 256;
    int to = t & 15, tj = t >> 4;
    float acc[4][4] = {};
    int lr = t >> 2, lk = (t & 3) * 4;
    for (int kk = kb; kk < kb + 256; kk += 16) {
        float4 wv = *(const float4*)(w + (size_t)(o0 + lr) * EDIM + kk + lk);
        float4 ev = *(const float4*)(emb + (size_t)(j0 + lr) * EDIM + kk + lk);
        __syncthreads();
        wt[lr * 17 + lk + 0] = wv.x; wt[lr * 17 + lk + 1] = wv.y;
        wt[lr * 17 + lk + 2] = wv.z; wt[lr * 17 + lk + 3] = wv.w;
        et[lr * 17 + lk + 0] = ev.x; et[lr * 17 + lk + 1] = ev.y;
        et[lr * 17 + lk + 2] = ev.z; et[lr * 17 + lk + 3] = ev.w;
        __syncthreads();
        #pragma unroll
        for (int k = 0; k < 16; k++) {
            float a[4], b[4];
            #pragma unroll
            for (int i = 0; i < 4; i++) a[i] = wt[(to * 4 + i) * 17 + k];
            #pragma unroll
            for (int i = 0; i < 4; i++) b[i] = et[(tj * 4 + i) * 17 + k];
            #pragma unroll
            for (int i = 0; i < 4; i++)
                #pragma unroll
                for (int jx = 0; jx < 4; jx++) acc[i][jx] += a[i] * b[jx];
        }
    }
    #pragma unroll
    for (int i = 0; i < 4; i++)
        #pragma unroll
        for (int jx = 0; jx < 4; jx++)
            atomicAdd(&T[(size_t)(o0 + to * 4 + i) * NE + j0 + tj * 4 + jx],
                      acc[i][jx]);
}

// ---------------- prep: emb fp32 -> eh bf16 [code][k] ----------------------
__global__ __launch_bounds__(256) void k_prep_e(const float* __restrict__ emb,
                                                unsigned short* __restrict__ eh) {
    int i = (blockIdx.x * 256 + threadIdx.x) * 4;
    float4 v = *(const float4*)(emb + i);
    uint2 hp;
    hp.x = (unsigned)f2bf(v.x) | ((unsigned)f2bf(v.y) << 16);
    hp.y = (unsigned)f2bf(v.z) | ((unsigned)f2bf(v.w) << 16);
    *(uint2*)(eh + i) = hp;
}

// ---------------- fused distance GEMM + argmin + tie-flagging --------------
// 1024 blocks x 128 thr (2 waves). Each block: 16 px, all 256 codes.
// Wave w handles K in [w*512, w*512+512); split-K combined through LDS once.
// A (z) converted fp32->bf16 inline in MFMA A-layout access order; B (eh)
// loaded per-fragment straight from L2 (eh = 512 KB, XCD-L2 resident).
// No per-chunk barriers.
__global__ __launch_bounds__(128, 2) void k_dist(
        const float* __restrict__ z, const unsigned short* __restrict__ eh,
        const float* __restrict__ ce2,
        int* __restrict__ idx_i, float* __restrict__ idx_f,
        int* __restrict__ hist, float* __restrict__ loss_s,
        float* __restrict__ zsq_acc,
        int* __restrict__ nflag, int* __restrict__ flagged) {
    __shared__ float accbuf[64 * 68];   // wave-1 acc spill, 68-stride vs conflicts
    int t = threadIdx.x;
    int lane = t & 63, w = t >> 6;
    int m = lane & 15, quad = lane >> 4;
    int px0 = blockIdx.x * 16;          // 16-px groups never cross a batch image
    int b = px0 >> 10;
    const float* zp = z + (((size_t)b) << 20) + (px0 & 1023) + m;  // + (c<<10)
    int k0 = w * 512;

    f32x4 acc[16];
    #pragma unroll
    for (int nt = 0; nt < 16; nt++) acc[nt] = (f32x4){0.f, 0.f, 0.f, 0.f};

    float zsq = 0.f;
    float zv[8];
    #pragma unroll
    for (int j = 0; j < 8; j++)         // prefetch A chunk 0
        zv[j] = zp[((size_t)(k0 + quad * 8 + j)) << 10];

    for (int ck = 0; ck < 16; ck++) {
        int kk = k0 + ck * 32;
        short8 bf[16];
        #pragma unroll
        for (int nt = 0; nt < 16; nt++)  // B frag: code = nt*16+m, k = kk+quad*8..+8
            bf[nt] = *(const short8*)(eh + (((size_t)(nt * 16 + m)) << 10) + kk + quad * 8);
        short8 af;
        #pragma unroll
        for (int j = 0; j < 8; j++) {
            zsq += zv[j] * zv[j];
            ((unsigned short*)&af)[j] = f2bf(zv[j]);
        }
        if (ck < 15) {
            #pragma unroll
            for (int j = 0; j < 8; j++)  // prefetch next A under this chunk's MFMAs
                zv[j] = zp[((size_t)(kk + 32 + quad * 8 + j)) << 10];
        }
        #pragma unroll
        for (int nt = 0; nt < 16; nt++)
            acc[nt] = __builtin_amdgcn_mfma_f32_16x16x32_bf16(af, bf[nt], acc[nt], 0, 0, 0);
    }

    // zsq: each wave covers disjoint (px,k) -> both waves contribute
    #pragma unroll
    for (int msk = 32; msk; msk >>= 1) zsq += __shfl_down(zsq, msk, 64);
    if (lane == 0) atomicAdd(zsq_acc, zsq);

    if (w == 1) {
        #pragma unroll
        for (int nt = 0; nt < 16; nt++)
            *(f32x4*)&accbuf[lane * 68 + nt * 4] = acc[nt];
    }
    __syncthreads();
    if (w == 0) {
        #pragma unroll
        for (int nt = 0; nt < 16; nt++) {
            f32x4 o = *(const f32x4*)&accbuf[lane * 68 + nt * 4];
            acc[nt][0] += o[0]; acc[nt][1] += o[1];
            acc[nt][2] += o[2]; acc[nt][3] += o[3];
        }
        float c2v[16];
        #pragma unroll
        for (int nt = 0; nt < 16; nt++) c2v[nt] = ce2[nt * 16 + m];

        float lsum = 0.f;
        #pragma unroll
        for (int r = 0; r < 4; r++) {    // D layout: row(px) = quad*4+r, col(code) = m
            float v1 = 3.4e38f, v2 = 3.4e38f; int i1 = 0;
            #pragma unroll
            for (int nt = 0; nt < 16; nt++) {
                int code = nt * 16 + m;
                float sv = c2v[nt] - acc[nt][r];   // 0.5||e||^2 - z.e
                if (sv < v1 || (sv == v1 && code < i1)) { v2 = v1; v1 = sv; i1 = code; }
                else v2 = fminf(v2, sv);
            }
            #pragma unroll
            for (int msk = 1; msk < 16; msk <<= 1) {
                float ov1 = __shfl_xor(v1, msk, 64);
                int   oi1 = __shfl_xor(i1, msk, 64);
                float ov2 = __shfl_xor(v2, msk, 64);
                float nv2 = fminf(fminf(v2, ov2), fmaxf(v1, ov1));
                if (ov1 < v1 || (ov1 == v1 && oi1 < i1)) { v1 = ov1; i1 = oi1; }
                v2 = nv2;
            }
            if (m == 0) {
                int px = px0 + quad * 4 + r;
                idx_i[px] = i1;
                idx_f[px] = (float)i1;
                atomicAdd(&hist[i1], 1);
                if (v2 - v1 < DELTA) {
                    int pos = atomicAdd(nflag, 1);
                    if (pos < MAXF) flagged[pos] = px;
                }
                lsum += v1;
            }
        }
        lsum += __shfl_xor(lsum, 16, 64);
        lsum += __shfl_xor(lsum, 32, 64);
        if (lane == 0) atomicAdd(loss_s, lsum);
    }
}

// ---------------- exact fp32 re-argmin for tie-flagged pixels --------------
__global__ __launch_bounds__(256) void k_cleanup(const float* __restrict__ z,
        const float* __restrict__ emb, const float* __restrict__ ce2,
        const int* __restrict__ nflag, const int* __restrict__ flagged,
        int* __restrict__ idx_i, float* __restrict__ idx_f, int* __restrict__ hist) {
    __shared__ float zs[1024];
    __shared__ float rv[4];
    __shared__ int ri[4];
    int t = threadIdx.x;
    int nf = *nflag; if (nf > MAXF) nf = MAXF;
    const float* er = emb + (size_t)t * EDIM;
    for (int i = blockIdx.x; i < nf; i += gridDim.x) {
        int px = flagged[i];
        int b = px >> 10, p = px & 1023;
        const float* zb = z + (((size_t)b) << 20) + p;
        #pragma unroll
        for (int r = 0; r < 4; r++) {
            int c = t + 256 * r;
            zs[c] = zb[((size_t)c) << 10];
        }
        __syncthreads();
        float d0 = 0.f, d1 = 0.f, d2 = 0.f, d3 = 0.f;
        #pragma unroll 4
        for (int c = 0; c < EDIM; c += 16) {
            float4 e0 = *(const float4*)(er + c);
            float4 e1 = *(const float4*)(er + c + 4);
            float4 e2 = *(const float4*)(er + c + 8);
            float4 e3 = *(const float4*)(er + c + 12);
            d0 += e0.x * zs[c]      + e0.y * zs[c + 1]  + e0.z * zs[c + 2]  + e0.w * zs[c + 3];
            d1 += e1.x * zs[c + 4]  + e1.y * zs[c + 5]  + e1.z * zs[c + 6]  + e1.w * zs[c + 7];
            d2 += e2.x * zs[c + 8]  + e2.y * zs[c + 9]  + e2.z * zs[c + 10] + e2.w * zs[c + 11];
            d3 += e3.x * zs[c + 12] + e3.y * zs[c + 13] + e3.z * zs[c + 14] + e3.w * zs[c + 15];
        }
        float sv = ce2[t] - ((d0 + d1) + (d2 + d3));
        int bi = t;
        #pragma unroll
        for (int msk = 1; msk < 64; msk <<= 1) {
            float ov = __shfl_xor(sv, msk, 64);
            int oi = __shfl_xor(bi, msk, 64);
            if (ov < sv || (ov == sv && oi < bi)) { sv = ov; bi = oi; }
        }
        if ((t & 63) == 0) { rv[t >> 6] = sv; ri[t >> 6] = bi; }
        __syncthreads();
        if (t == 0) {
            float v = rv[0]; int ix = ri[0];
            for (int ww = 1; ww < 4; ww++)
                if (rv[ww] < v || (rv[ww] == v && ri[ww] < ix)) { v = rv[ww]; ix = ri[ww]; }
            int old = idx_i[px];
            if (ix != old) {
                idx_i[px] = ix; idx_f[px] = (float)ix;
                atomicAdd(&hist[ix], 1); atomicSub(&hist[old], 1);
            }
        }
        __syncthreads();
    }
}

// ---------------- round-1 fp32 argmin (fallback only) ----------------------
__global__ __launch_bounds__(256) void k_argmin(const float* __restrict__ z,
                                                const float* __restrict__ emb,
                                                const float* __restrict__ ce2,
                                                int* __restrict__ idx_i,
                                                float* __restrict__ idx_f,
                                                int* __restrict__ hist,
                                                float* __restrict__ loss_acc) {
    __shared__ float zt[32 * 64];
    __shared__ float et[256 * 34];
    __shared__ float znorm_s[64];
    int t = threadIdx.x;
    int n0 = blockIdx.x * 64;
    int b = n0 >> 10;
    int p0 = n0 & 1023;
    const float* zb = z + (size_t)b * EDIM * HW;
    int tc = t & 31, tp = t >> 5;
    float acc[8][8] = {};
    float znorm = 0.f;
    for (int kk = 0; kk < EDIM; kk += 32) {
        #pragma unroll
        for (int i = 0; i < 16; i++) {
            int q = t + 256 * i;
            int code = q >> 4, k2 = q & 15;
            float2 v = *(const float2*)(emb + (size_t)code * EDIM + kk + k2 * 2);
            *(float2*)(et + code * 34 + k2 * 2) = v;
        }
        #pragma unroll
        for (int i = 0; i < 4; i++) {
            int q = t + 256 * i;
            int k = q >> 5, p2 = q & 31;
            float2 v = *(const float2*)(zb + (size_t)(kk + k) * HW + p0 + p2 * 2);
            *(float2*)(zt + k * 64 + p2 * 2) = v;
        }
        __syncthreads();
        if (t < 64) {
            #pragma unroll
            for (int k = 0; k < 32; k++) { float zz = zt[k * 64 + t]; znorm += zz * zz; }
        }
        #pragma unroll 4
        for (int k2 = 0; k2 < 16; k2++) {
            float2 ev[8], za[4], zb2[4];
            #pragma unroll
            for (int u = 0; u < 8; u++)
                ev[u] = *(float2*)(et + (tc + 32 * u) * 34 + k2 * 2);
            #pragma unroll
            for (int j = 0; j < 4; j++)
                za[j] = *(float2*)(zt + (2 * k2) * 64 + tp * 8 + 2 * j);
            #pragma unroll
            for (int j = 0; j < 4; j++)
                zb2[j] = *(float2*)(zt + (2 * k2 + 1) * 64 + tp * 8 + 2 * j);
            #pragma unroll
            for (int p = 0; p < 8; p++) {
                float z0 = (p & 1) ? za[p >> 1].y : za[p >> 1].x;
                float z1 = (p & 1) ? zb2[p >> 1].y : zb2[p >> 1].x;
                #pragma unroll
                for (int u = 0; u < 8; u++)
                    acc[p][u] += z0 * ev[u].x + z1 * ev[u].y;
            }
        }
        __syncthreads();
    }
    if (t < 64) znorm_s[t] = znorm;
    float minv[8];
    int mini[8];
    #pragma unroll
    for (int p = 0; p < 8; p++) { minv[p] = 3.4e38f; mini[p] = 0; }
    #pragma unroll
    for (int u = 0; u < 8; u++) {
        int code = tc + 32 * u;
        float cc2 = ce2[code];
        #pragma unroll
        for (int p = 0; p < 8; p++) {
            float s = cc2 - acc[p][u];
            if (s < minv[p] || (s == minv[p] && code < mini[p])) { minv[p] = s; mini[p] = code; }
        }
    }
    #pragma unroll
    for (int m = 1; m < 32; m <<= 1) {
        #pragma unroll
        for (int p = 0; p < 8; p++) {
            float ov = __shfl_xor(minv[p], m, 64);
            int oi = __shfl_xor(mini[p], m, 64);
            if (ov < minv[p] || (ov == minv[p] && oi < mini[p])) { minv[p] = ov; mini[p] = oi; }
        }
    }
    __syncthreads();
    if (tc == 0) {
        float dsum = 0.f;
        #pragma unroll
        for (int p = 0; p < 8; p++) {
            int lp = tp * 8 + p;
            int n = n0 + lp;
            idx_i[n] = mini[p];
            idx_f[n] = (float)mini[p];
            dsum += znorm_s[lp] + 2.f * minv[p];
            atomicAdd(&hist[mini[p]], 1);
        }
        atomicAdd(loss_acc, dsum);
    }
}

// ---------------- out[b][o][p] = T[o][idx[b][p]] + bias[o] -----------------
__global__ __launch_bounds__(256) void k_scatter(const float* __restrict__ T,
                                                 const float* __restrict__ bias,
                                                 const int* __restrict__ idx,
                                                 float* __restrict__ out) {
    int t = threadIdx.x;
    int og = blockIdx.x;
    int b = blockIdx.y;
    int4 i4 = *(const int4*)(idx + b * HW + t * 4);
    #pragma unroll
    for (int j = 0; j < 4; j++) {
        int o = og * 4 + j;
        const float* Tr = T + (size_t)o * NE;
        float bb = bias[o];
        float4 r;
        r.x = Tr[i4.x] + bb;
        r.y = Tr[i4.y] + bb;
        r.z = Tr[i4.z] + bb;
        r.w = Tr[i4.w] + bb;
        *(float4*)(out + ((size_t)(b * EDIM + o) * HW) + t * 4) = r;
    }
}

// ---------------- finalize -------------------------------------------------
__global__ __launch_bounds__(256) void k_final_new(const int* __restrict__ hist,
                                                   const float* __restrict__ loss_s,
                                                   const float* __restrict__ zsq,
                                                   float* __restrict__ out) {
    __shared__ float red[4];
    int t = threadIdx.x;
    float em = (float)hist[t] * (1.0f / 16384.0f);
    float v = em * logf(em + 1e-10f);
    #pragma unroll
    for (int m = 32; m; m >>= 1) v += __shfl_down(v, m, 64);
    if ((t & 63) == 0) red[t >> 6] = v;
    __syncthreads();
    if (t == 0) {
        float s = red[0] + red[1] + red[2] + red[3];
        out[OUT_ELEMS] = (zsq[0] + 2.f * loss_s[0]) * 1.25f / 16777216.f;
        out[OUT_ELEMS + 1] = expf(-s);
    }
}

__global__ __launch_bounds__(256) void k_final_old(const int* __restrict__ hist,
                                                   const float* __restrict__ loss_acc,
                                                   float* __restrict__ out) {
    __shared__ float red[4];
    int t = threadIdx.x;
    float em = (float)hist[t] * (1.0f / 16384.0f);
    float v = em * logf(em + 1e-10f);
    #pragma unroll
    for (int m = 32; m; m >>= 1) v += __shfl_down(v, m, 64);
    if ((t & 63) == 0) red[t >> 6] = v;
    __syncthreads();
    if (t == 0) {
        float s = red[0] + red[1] + red[2] + red[3];
        out[OUT_ELEMS] = loss_acc[0] * 1.25f / 16777216.f;
        out[OUT_ELEMS + 1] = expf(-s);
    }
}

extern "C" void kernel_launch(void* const* d_in, const int* in_sizes, int n_in,
                              void* d_out, int out_size, void* d_ws, size_t ws_size,
                              hipStream_t stream) {
    (void)in_sizes; (void)n_in; (void)out_size;
    const float* z      = (const float*)d_in[0];
    const float* emb    = (const float*)d_in[1];
    const float* conv_w = (const float*)d_in[2];
    const float* conv_b = (const float*)d_in[3];
    float* out = (float*)d_out;

    if (ws_size >= WS_NEED) {
        // ---- fast path: fused bf16 MFMA distance GEMM, no global scratch ----
        int*   hist     = (int*)((char*)d_ws + WS_HIST);
        float* loss_s   = (float*)((char*)d_ws + WS_LOSS);
        float* zsq      = (float*)((char*)d_ws + WS_ZSQ);
        int*   nflag    = (int*)((char*)d_ws + WS_NFLAG);
        float* T        = (float*)((char*)d_ws + WS_T);
        float* ce2      = (float*)((char*)d_ws + WS_CE2);
        int*   flagged  = (int*)((char*)d_ws + WS_FLAG);
        int*   idx_i    = (int*)((char*)d_ws + WS_IDX);
        unsigned short* eh = (unsigned short*)((char*)d_ws + WS_EH);
        float* idx_f = out + OUT_ELEMS + 2;

        hipMemsetAsync(d_ws, 0, WS_MEMSET, stream);
        k_prep_e<<<256, 256, 0, stream>>>(emb, eh);
        k_norms<<<NE, 64, 0, stream>>>(emb, ce2);
        k_wT<<<dim3(4, 16, 4), 256, 0, stream>>>(conv_w, emb, T);
        k_dist<<<1024, 128, 0, stream>>>(z, eh, ce2, idx_i, idx_f,
                                         hist, loss_s, zsq, nflag, flagged);
        k_cleanup<<<256, 256, 0, stream>>>(z, emb, ce2, nflag, flagged,
                                           idx_i, idx_f, hist);
        k_scatter<<<dim3(256, 16), 256, 0, stream>>>(T, conv_b, idx_i, out);
        k_final_new<<<1, 256, 0, stream>>>(hist, loss_s, zsq, out);
    } else {
        // ---- fallback: round-1 fp32 path ----
        float* ce2      = (float*)((char*)d_ws + WO_CE2);
        int*   hist     = (int*)((char*)d_ws + WO_HIST);
        float* loss_acc = (float*)((char*)d_ws + WO_LOSS);
        int*   idx_i    = (int*)((char*)d_ws + WO_IDX);
        float* T        = (float*)((char*)d_ws + WO_T);
        float* idx_f = out + OUT_ELEMS + 2;

        hipMemsetAsync(d_ws, 0, WO_TOTAL, stream);
        k_norms<<<NE, 64, 0, stream>>>(emb, ce2);
        k_wT<<<dim3(4, 16, 4), 256, 0, stream>>>(conv_w, emb, T);
        k_argmin<<<256, 256, 0, stream>>>(z, emb, ce2, idx_i, idx_f, hist, loss_acc);
        k_scatter<<<dim3(256, 16), 256, 0, stream>>>(T, conv_b, idx_i, out);
        k_final_old<<<1, 256, 0, stream>>>(hist, loss_acc, out);
    }
}